// Round 1
// baseline (289.820 us; speedup 1.0000x reference)
//
#include <hip/hip_runtime.h>
#include <hip/hip_bf16.h>

// GCN 2-layer encoder, MI355X (gfx950).
// Known: float tensors bf16, edge_index int64 (self-detection kept).
// Round 12: L2-resident chunked gathers. Gather tables (xs, h2s) stored
// chunk-major [4][Npad][32] (3.2MB/chunk < 4MiB per-XCD L2). agg kernels do
// 4 chunk passes (chunk-major block order -> temporal separation); per-wave
// layout 16 edge-groups x 4 lanes x 16B. gemm12 A-loads/h2s-stores re-addressed
// (A-frag loads now fully contiguous 1KB/wave).
// 6 dispatches.
// Pipeline:
//   memset bcnt -> k_pe (edges bucketing + weight prep + flags)
//   k_bsort(+scan +prescale xs=dinv*x, chunk-major): CSR/offsets/dinv/xs
//   a1[c][v] = dinv[v]*(xs[c][v] + sum xs[c][csr])  [chunked gather]
//   h2s = (relu(a1@W1+b1) @ W2) * dinv[row]          [fused MFMA, LDS h1]
//   out[v] = dinv[v]*(h2s[:, v] + sum h2s[:, csr]) + b2 [chunked gather]

typedef __bf16 bf16x8v __attribute__((ext_vector_type(8)));
typedef short  s16x8   __attribute__((ext_vector_type(8)));
typedef float  f32x4   __attribute__((ext_vector_type(4)));

#define IN_DIM 128
#define HID    256
#define OUTD   128
#define BKT_SHIFT 7
#define BKT_NODES 128
#define MAXB 512            // max buckets (N <= 65536)
#define CAP  8192           // per-bucket capacity (mean 2046, 40+ sigma margin)
#define EBLK 512            // edge-bucketing blocks in k_pe
#define NCHUNK 4            // feature chunks (32 cols = 64B/row, 3.2MB/chunk)
#define AGG_CBLK 2048       // blocks per chunk in agg kernels

__device__ __forceinline__ float2 bf2f(__hip_bfloat162 v) {
    return make_float2(__bfloat162float(v.x), __bfloat162float(v.y));
}
__device__ __forceinline__ __hip_bfloat162 f2bf(float a, float b) {
    __hip_bfloat162 r; r.x = __float2bfloat16(a); r.y = __float2bfloat16(b); return r;
}
__device__ __forceinline__ void acc_row(float* acc, s16x8 r) {
    __hip_bfloat162* p = (__hip_bfloat162*)&r;
#pragma unroll
    for (int j = 0; j < 4; ++j) {
        float2 f = bf2f(p[j]);
        acc[2 * j]     += f.x;
        acc[2 * j + 1] += f.y;
    }
}

// dtype self-detection (W2 uniform +-1/16: any bf16-exp >= 0x7F => fp32)
__device__ __forceinline__ int detect_f32(const void* W2raw) {
    const unsigned short* u = (const unsigned short*)W2raw;
    int f32 = 0;
#pragma unroll
    for (int i = 0; i < 64; ++i) {
        unsigned e = (u[i] >> 7) & 0xFF;
        if (e >= 0x7F) f32 = 1;
    }
    return f32;
}
__device__ __forceinline__ int detect_i64(const void* eiraw) {
    const unsigned* ip = (const unsigned*)eiraw;
    unsigned orodd = 0;
#pragma unroll
    for (int i = 0; i < 64; ++i) orodd |= ip[2 * i + 1];
    return (orodd == 0) ? 1 : 0;
}

__device__ __forceinline__ short ldw(const void* raw, int idx, int f32) {
    if (f32) {
        __hip_bfloat16 h = __float2bfloat16(((const float*)raw)[idx]);
        return *(short*)&h;
    }
    return ((const short*)raw)[idx];
}

template <int K, int NN>
__device__ __forceinline__ void swz_one(const void* Wraw, int f32,
                                        short* __restrict__ Bsw, int tid) {
    constexpr int KC = K / 32;
    constexpr int NT = NN / 16;
    if (tid >= NT * KC * 64) return;
    int lane = tid & 63;
    int kc   = (tid >> 6) % KC;
    int nt   = tid / (64 * KC);
    int n  = nt * 16 + (lane & 15);
    int kb = kc * 32 + (lane >> 4) * 8;
    s16x8 v;
#pragma unroll
    for (int j = 0; j < 8; ++j) v[j] = ldw(Wraw, (kb + j) * NN + n, f32);
    ((s16x8*)Bsw)[tid] = v;
}

// ---------------- fused: edge bucketing + weight prep + flags ----------------

__global__ __launch_bounds__(256) void k_pe(
        const void* __restrict__ ei_, int E, int N, int NB,
        int* __restrict__ bcnt, unsigned* __restrict__ ppack,
        const void* W1raw, const void* b1raw, const void* W2raw, const void* b2raw,
        short* __restrict__ Bsw1, short* __restrict__ Bsw2,
        __hip_bfloat16* __restrict__ b1c, __hip_bfloat16* __restrict__ b2c,
        int* __restrict__ flags) {
    int blk = blockIdx.x, t = threadIdx.x;
    if (blk >= EBLK) {
        int f32 = detect_f32(W2raw);
        int pb = blk - EBLK;
        if (pb < 16) {
            swz_one<IN_DIM, HID>(W1raw, f32, Bsw1, pb * 256 + t);
        } else if (pb < 32) {
            swz_one<HID, OUTD>(W2raw, f32, Bsw2, (pb - 16) * 256 + t);
        } else {
            short s1 = ldw(b1raw, t, f32);
            b1c[t] = *(__hip_bfloat16*)&s1;
            if (t < OUTD) {
                short s2 = ldw(b2raw, t, f32);
                b2c[t] = *(__hip_bfloat16*)&s2;
            }
            if (t == 0) {
                flags[0] = f32;
                flags[1] = detect_i64(ei_);
            }
        }
        return;
    }
    __shared__ int lhist[4][MAXB];
    __shared__ int lbase[4][MAXB];
    int wv = t >> 6;
    int i64 = detect_i64(ei_);
    const long long* p64 = (const long long*)ei_;
    const int*       p32 = (const int*)ei_;
    int per = (E + EBLK - 1) / EBLK;
    int e0 = blk * per, e1 = min(e0 + per, E);
    for (int i = t; i < NB; i += 256) {
        lhist[0][i] = 0; lhist[1][i] = 0; lhist[2][i] = 0; lhist[3][i] = 0;
    }
    __syncthreads();
    for (int e = e0 + t; e < e1; e += 256) {
        int d = i64 ? (int)p64[E + e] : p32[E + e];
        if ((unsigned)d >= (unsigned)N) d = 0;
        atomicAdd(&lhist[wv][((unsigned)d) >> BKT_SHIFT], 1);
    }
    __syncthreads();
    for (int i = t; i < NB; i += 256) {
        int c0 = lhist[0][i], c1 = lhist[1][i], c2 = lhist[2][i], c3 = lhist[3][i];
        int tot = c0 + c1 + c2 + c3;
        int g = tot ? atomicAdd(&bcnt[i], tot) : 0;
        lbase[0][i] = g;
        lbase[1][i] = g + c0;
        lbase[2][i] = g + c0 + c1;
        lbase[3][i] = g + c0 + c1 + c2;
        lhist[0][i] = 0; lhist[1][i] = 0; lhist[2][i] = 0; lhist[3][i] = 0;
    }
    __syncthreads();
    for (int e = e0 + t; e < e1; e += 256) {
        int d = i64 ? (int)p64[E + e] : p32[E + e];
        int s = i64 ? (int)p64[e]     : p32[e];
        if ((unsigned)d >= (unsigned)N) d = 0;
        if ((unsigned)s >= (unsigned)N) s = 0;
        int b = ((unsigned)d) >> BKT_SHIFT;
        int pos = lbase[wv][b] + atomicAdd(&lhist[wv][b], 1);
        if (pos < CAP)
            ppack[(size_t)b * CAP + pos] = ((unsigned)(d & (BKT_NODES - 1)) << 25) | (unsigned)s;
    }
}

// ---------------- bucket sort (+bucket scan, +prescale xs chunk-major) -------

__global__ __launch_bounds__(512) void k_bsort(const int* __restrict__ bcnt,
                                               const unsigned* __restrict__ ppack,
                                               int NB,
                                               int* __restrict__ csr, int* __restrict__ offsets,
                                               float* __restrict__ dinv, int N, int Npad,
                                               const void* __restrict__ xraw,
                                               const int* __restrict__ flags,
                                               __hip_bfloat16* __restrict__ xs) {
    __shared__ int sb[MAXB];
    __shared__ int h[BKT_NODES], base[BKT_NODES], s[BKT_NODES];
    __shared__ float sdv[BKT_NODES];
    int b = blockIdx.x;
    int t = threadIdx.x;
    int c = (t < NB) ? min(bcnt[t], CAP) : 0;
    sb[t] = c;
    __syncthreads();
    for (int off = 1; off < MAXB; off <<= 1) {
        int u = (t >= off) ? sb[t - off] : 0;
        __syncthreads();
        sb[t] += u;
        __syncthreads();
    }
    int cnt   = min(bcnt[b], CAP);
    int ebase = sb[b] - cnt;
    if (b == NB - 1 && t == 0) offsets[N] = sb[b];
    const unsigned* pp = ppack + (size_t)b * CAP;
    if (t < BKT_NODES) h[t] = 0;
    __syncthreads();
    for (int e = t; e < cnt; e += 512) atomicAdd(&h[pp[e] >> 25], 1);
    __syncthreads();
    int v = (t < BKT_NODES) ? h[t] : 0;
    if (t < BKT_NODES) s[t] = v;
    __syncthreads();
    for (int off = 1; off < BKT_NODES; off <<= 1) {
        int u = (t < BKT_NODES && t >= off) ? s[t - off] : 0;
        __syncthreads();
        if (t < BKT_NODES) s[t] += u;
        __syncthreads();
    }
    if (t < BKT_NODES) {
        int excl = s[t] - v;
        base[t] = excl;
        int node = b * BKT_NODES + t;
        float dv = 0.f;
        if (node < N) {
            dv = rsqrtf((float)(v + 1));
            offsets[node] = ebase + excl;
            dinv[node] = dv;
        } else {
            dinv[node] = 0.f;
        }
        sdv[t] = dv;
        h[t] = 0;
    }
    __syncthreads();
    for (int e = t; e < cnt; e += 512) {
        unsigned pk = pp[e];
        int ld = pk >> 25;
        int pos = ebase + base[ld] + atomicAdd(&h[ld], 1);
        csr[pos] = (int)(pk & 0x1FFFFFFu);
    }
    // fused prescale: xs rows [b*128, b*128+128) = dinv * x, chunk-major layout
    // xs[c][node][32] : s16x8 index = (c*Npad + node)*4 + (slice&3)
    int f32 = flags[0];
    if (!f32) {
        const s16x8* xg = (const s16x8*)xraw;
        s16x8* xo = (s16x8*)xs;
        for (int u = t; u < BKT_NODES * 16; u += 512) {
            int row = u >> 4;
            int sl  = u & 15;
            int node = b * BKT_NODES + row;
            float dv = sdv[row];
            s16x8 val = {0, 0, 0, 0, 0, 0, 0, 0};
            if (node < N) {
                s16x8 xin = xg[(size_t)node * 16 + sl];
                __hip_bfloat162* xp = (__hip_bfloat162*)&xin;
                __hip_bfloat162* vp = (__hip_bfloat162*)&val;
#pragma unroll
                for (int j = 0; j < 4; ++j) {
                    float2 f = bf2f(xp[j]);
                    vp[j] = f2bf(dv * f.x, dv * f.y);
                }
            }
            xo[((size_t)(sl >> 2) * Npad + node) * 4 + (sl & 3)] = val;
        }
    } else {
        const float4* xg = (const float4*)xraw;
        __hip_bfloat162* xo = (__hip_bfloat162*)xs;
        for (int u = t; u < BKT_NODES * 32; u += 512) {
            int row = u >> 5;
            int q   = u & 31;           // float4 index within row (cols 4q..4q+3)
            int node = b * BKT_NODES + row;
            float dv = sdv[row];
            __hip_bfloat162 v0 = f2bf(0.f, 0.f), v1 = v0;
            if (node < N) {
                float4 xin = xg[(size_t)node * 32 + q];
                v0 = f2bf(dv * xin.x, dv * xin.y);
                v1 = f2bf(dv * xin.z, dv * xin.w);
            }
            size_t bi = ((size_t)(q >> 3) * Npad + node) * 16 + (q & 7) * 2;
            xo[bi]     = v0;
            xo[bi + 1] = v1;
        }
    }
}

// ---------------- aggregation 1 (chunked grouped gather) ----------------
// chunk-major block order: blocks [c*AGG_CBLK, (c+1)*AGG_CBLK) handle chunk c
// (3.2MB table slice -> per-XCD L2 resident). 4 lanes per row (16B/lane),
// 16 edge-groups per wave, shfl_xor combine.

__global__ __launch_bounds__(256) void k_agg1(
        const s16x8* __restrict__ xs8, const int* __restrict__ offsets,
        const int* __restrict__ csr, const float* __restrict__ dinv,
        s16x8* __restrict__ a8, int N, int Npad, int nwaves) {
    int chunk = blockIdx.x / AGG_CBLK;
    int cb    = blockIdx.x % AGG_CBLK;
    int gw   = cb * 4 + (threadIdx.x >> 6);
    int lane = threadIdx.x & 63;
    int g = lane >> 2, li = lane & 3;
    const s16x8* xc = xs8 + (size_t)chunk * Npad * 4;
    s16x8*       ac = a8  + (size_t)chunk * Npad * 4;
    for (int v = gw; v < Npad; v += nwaves) {
        if (v >= N) {
            if (g == 0) { s16x8 z = {0,0,0,0,0,0,0,0}; ac[(size_t)v * 4 + li] = z; }
            continue;
        }
        float acc[8];
#pragma unroll
        for (int j = 0; j < 8; ++j) acc[j] = 0.f;
        int o0 = offsets[v], o1 = offsets[v + 1];
        if (g == 0) acc_row(acc, xc[(size_t)v * 4 + li]);   // self (pre-scaled)
        for (int e = o0 + g; e < o1; e += 16)
            acc_row(acc, xc[(size_t)csr[e] * 4 + li]);
#pragma unroll
        for (int j = 0; j < 8; ++j) {
            acc[j] += __shfl_xor(acc[j], 4, 64);
            acc[j] += __shfl_xor(acc[j], 8, 64);
            acc[j] += __shfl_xor(acc[j], 16, 64);
            acc[j] += __shfl_xor(acc[j], 32, 64);
        }
        if (g == 0) {
            float dv = dinv[v];
            s16x8 outv;
            __hip_bfloat162* op = (__hip_bfloat162*)&outv;
#pragma unroll
            for (int j = 0; j < 4; ++j) op[j] = f2bf(dv * acc[2 * j], dv * acc[2 * j + 1]);
            ac[(size_t)v * 4 + li] = outv;
        }
    }
}

// ---------------- fused MFMA GEMM1+GEMM2 (64-row tiles) ----------------
// Block = 4 waves, 64 rows/tile, wave owns 16 rows. Phase 1: h1 = relu(A@W1+b1)
// into XOR-swizzled LDS (per-wave-private rows, no barrier). Phase 2:
// h2s = (h1@W2)*dinv. A read + h2s write use chunk-major [4][Npad][32] layout.

__global__ __launch_bounds__(256) void k_gemm12(
        const __hip_bfloat16* __restrict__ A, const __hip_bfloat16* __restrict__ Bsw1,
        const __hip_bfloat16* __restrict__ b1c, const __hip_bfloat16* __restrict__ Bsw2,
        const float* __restrict__ dinv, __hip_bfloat16* __restrict__ h2s, int Npad) {
    __shared__ __align__(16) __hip_bfloat16 hl[64 * HID];   // 32 KB
    int wave = threadIdx.x >> 6, lane = threadIdx.x & 63;
    int quad = lane >> 4, l16 = lane & 15;
    int mw = wave * 16;                    // wave row base in tile
    int gm = blockIdx.x * 64 + mw;         // global row base

    // phase 1 (A chunk kc = cols kc*32..kc*32+32)
    bf16x8v a1f[4];
#pragma unroll
    for (int kc = 0; kc < 4; ++kc)
        a1f[kc] = *reinterpret_cast<const bf16x8v*>(
            A + ((size_t)kc * Npad + gm + l16) * 32 + quad * 8);

    const bf16x8v* B1 = reinterpret_cast<const bf16x8v*>(Bsw1);
    for (int nt = 0; nt < HID / 16; ++nt) {
        f32x4 acc = {0.f, 0.f, 0.f, 0.f};
#pragma unroll
        for (int kc = 0; kc < 4; ++kc)
            acc = __builtin_amdgcn_mfma_f32_16x16x32_bf16(a1f[kc], B1[(nt * 4 + kc) * 64 + lane], acc, 0, 0, 0);
        int col = nt * 16 + l16;
        int gcol = col >> 3, csub = col & 7;
        float bv = __bfloat162float(b1c[col]);
#pragma unroll
        for (int r = 0; r < 4; ++r) {
            float v0 = acc[r] + bv; v0 = v0 > 0.f ? v0 : 0.f;
            int r0 = mw + quad * 4 + r;
            ((__hip_bfloat16*)((char*)hl + (size_t)r0 * (HID * 2) + ((gcol ^ (r0 & 31)) << 4)))[csub] = __float2bfloat16(v0);
        }
    }
    // per-wave-private rows: no __syncthreads needed

    // phase 2
    bf16x8v a2f[8];
#pragma unroll
    for (int kc = 0; kc < 8; ++kc) {
        int row = mw + l16;
        int g = (kc * 4 + quad) ^ (row & 31);
        a2f[kc] = *reinterpret_cast<const bf16x8v*>(
            (char*)hl + (size_t)row * (HID * 2) + ((size_t)g << 4));
    }
    const bf16x8v* B2 = reinterpret_cast<const bf16x8v*>(Bsw2);
    int rb0 = gm + quad * 4;
    float sc0[4];
#pragma unroll
    for (int r = 0; r < 4; ++r) sc0[r] = dinv[rb0 + r];
    for (int nt = 0; nt < OUTD / 16; ++nt) {
        f32x4 acc = {0.f, 0.f, 0.f, 0.f};
#pragma unroll
        for (int kc = 0; kc < 8; ++kc)
            acc = __builtin_amdgcn_mfma_f32_16x16x32_bf16(a2f[kc], B2[(nt * 8 + kc) * 64 + lane], acc, 0, 0, 0);
        int col = nt * 16 + l16;
#pragma unroll
        for (int r = 0; r < 4; ++r)
            h2s[((size_t)(nt >> 1) * Npad + rb0 + r) * 32 + (col & 31)] = __float2bfloat16(acc[r] * sc0[r]);
    }
}

// ---------------- aggregation 2 (chunked grouped gather) ----------------

__global__ __launch_bounds__(256) void k_agg2(
        const s16x8* __restrict__ h8, const int* __restrict__ offsets,
        const int* __restrict__ csr, const float* __restrict__ dinv,
        const __hip_bfloat16* __restrict__ b2c, const int* __restrict__ flags,
        void* __restrict__ outraw, int N, int Npad, int nwaves) {
    int chunk = blockIdx.x / AGG_CBLK;
    int cb    = blockIdx.x % AGG_CBLK;
    int gw   = cb * 4 + (threadIdx.x >> 6);
    int lane = threadIdx.x & 63;
    int g = lane >> 2, li = lane & 3;
    int f32 = flags[0];
    const s16x8* hc = h8 + (size_t)chunk * Npad * 4;
    float bb[8];
    {
        s16x8 bv = ((const s16x8*)b2c)[chunk * 4 + li];
        __hip_bfloat162* bp = (__hip_bfloat162*)&bv;
#pragma unroll
        for (int j = 0; j < 4; ++j) {
            float2 f = bf2f(bp[j]);
            bb[2 * j] = f.x; bb[2 * j + 1] = f.y;
        }
    }
    for (int v = gw; v < N; v += nwaves) {
        float acc[8];
#pragma unroll
        for (int j = 0; j < 8; ++j) acc[j] = 0.f;
        int o0 = offsets[v], o1 = offsets[v + 1];
        if (g == 0) acc_row(acc, hc[(size_t)v * 4 + li]);    // self (pre-scaled)
        for (int e = o0 + g; e < o1; e += 16)
            acc_row(acc, hc[(size_t)csr[e] * 4 + li]);
#pragma unroll
        for (int j = 0; j < 8; ++j) {
            acc[j] += __shfl_xor(acc[j], 4, 64);
            acc[j] += __shfl_xor(acc[j], 8, 64);
            acc[j] += __shfl_xor(acc[j], 16, 64);
            acc[j] += __shfl_xor(acc[j], 32, 64);
        }
        if (g == 0) {
            float dv = dinv[v];
            if (f32) {
                float4* of = (float4*)outraw;
                float4 o0v = {dv * acc[0] + bb[0], dv * acc[1] + bb[1],
                              dv * acc[2] + bb[2], dv * acc[3] + bb[3]};
                float4 o1v = {dv * acc[4] + bb[4], dv * acc[5] + bb[5],
                              dv * acc[6] + bb[6], dv * acc[7] + bb[7]};
                of[(size_t)v * 32 + chunk * 8 + li * 2]     = o0v;
                of[(size_t)v * 32 + chunk * 8 + li * 2 + 1] = o1v;
            } else {
                s16x8 outv;
                __hip_bfloat162* op = (__hip_bfloat162*)&outv;
#pragma unroll
                for (int j = 0; j < 4; ++j)
                    op[j] = f2bf(dv * acc[2 * j] + bb[2 * j], dv * acc[2 * j + 1] + bb[2 * j + 1]);
                ((s16x8*)outraw)[(size_t)v * 16 + chunk * 4 + li] = outv;
            }
        }
    }
}

// ---------------- host launch ----------------

extern "C" void kernel_launch(void* const* d_in, const int* in_sizes, int n_in,
                              void* d_out, int out_size, void* d_ws, size_t ws_size,
                              hipStream_t stream) {
    const void* x  = d_in[0];
    const void* ei = d_in[1];
    const void* W1 = d_in[2];
    const void* b1 = d_in[3];
    const void* W2 = d_in[4];
    const void* b2 = d_in[5];

    const int N = in_sizes[0] / IN_DIM;       // 50000
    const int E = in_sizes[1] / 2;            // 800000
    const int Npad = ((N + 127) / 128) * 128; // 50048 (multiple of 128)
    const int NB = Npad / BKT_NODES;          // 391

    char* w = (char*)d_ws;
    auto alloc = [&](size_t bytes) -> void* {
        void* p = (void*)w;
        w += (bytes + 255) / 256 * 256;
        return p;
    };
    int*   flags   = (int*)alloc(256);
    int*   bcnt    = (int*)alloc((size_t)MAXB * 4);
    int*   offsets = (int*)alloc((size_t)(N + 1) * 4);
    float* dinv    = (float*)alloc((size_t)Npad * 4);
    unsigned* ppack = (unsigned*)alloc((size_t)NB * CAP * 4);
    int*   csr     = (int*)alloc((size_t)E * 4);
    short* Bsw1 = (short*)alloc((size_t)IN_DIM * HID * 2);
    short* Bsw2 = (short*)alloc((size_t)HID * OUTD * 2);
    __hip_bfloat16* b1c = (__hip_bfloat16*)alloc((size_t)HID * 2);
    __hip_bfloat16* b2c = (__hip_bfloat16*)alloc((size_t)OUTD * 2);
    __hip_bfloat16* xs  = (__hip_bfloat16*)alloc((size_t)Npad * IN_DIM * 2);
    __hip_bfloat16* a1  = (__hip_bfloat16*)alloc((size_t)Npad * IN_DIM * 2);
    __hip_bfloat16* h2s = xs;   // xs dead after agg1; reuse for gemm12 output

    hipMemsetAsync(bcnt, 0, (size_t)MAXB * 4, stream);

    k_pe<<<EBLK + 33, 256, 0, stream>>>(ei, E, N, NB, bcnt, ppack,
                                        W1, b1, W2, b2, Bsw1, Bsw2, b1c, b2c, flags);

    k_bsort<<<NB, 512, 0, stream>>>(bcnt, ppack, NB, csr, offsets, dinv, N, Npad,
                                    x, flags, xs);

    const int aggBlocks = NCHUNK * AGG_CBLK, nwaves = AGG_CBLK * 4;
    k_agg1<<<aggBlocks, 256, 0, stream>>>((const s16x8*)xs, offsets, csr, dinv,
                                          (s16x8*)a1, N, Npad, nwaves);

    k_gemm12<<<Npad / 64, 256, 0, stream>>>(a1, (const __hip_bfloat16*)Bsw1, b1c,
                                            (const __hip_bfloat16*)Bsw2, dinv, h2s, Npad);

    k_agg2<<<aggBlocks, 256, 0, stream>>>((const s16x8*)h2s, offsets, csr, dinv,
                                          b2c, flags, d_out, N, Npad, nwaves);
}

// Round 4
// 211.642 us; speedup vs baseline: 1.3694x; 1.3694x over previous
//
#include <hip/hip_runtime.h>
#include <hip/hip_bf16.h>

// GCN 2-layer encoder, MI355X (gfx950).
// Known: float tensors bf16, edge_index int64 (self-detection kept).
// Round 15: r13's fused k_aggemm (shfl redistribution) implicated in replay
// divergence (single-edge-magnitude error, intermittent) -> dropped. Split
// pipeline restored from r11/r0 (k_pe, k_bsort, k_gemm12 byte-identical).
// Kept from r13 (mathematically exact, boring):
//  - per-group-node aggregation: 16-lane group owns one node, contiguous csr,
//    no shfl butterfly, no idle epilogue lanes, 256B coalesced writes
//  - nontemporal csr loads + final-out stores, 32-bit gather addressing
// 6 dispatches.
// Pipeline:
//   memset bcnt -> k_pe (edges bucketing + weight prep + flags)
//   k_bsort(+scan +prescale xs=dinv*x): CSR/offsets/dinv/xs
//   k_agg1: a1[v] = dinv[v]*(xs[v] + sum xs[csr])      [per-group-node gather]
//   k_gemm12: h2s = (relu(a1@W1+b1) @ W2) * dinv[row]  [fused MFMA, LDS h1]
//   k_agg2: out[v] = dinv[v]*(h2s[v] + sum h2s[csr]) + b2

typedef __bf16 bf16x8v __attribute__((ext_vector_type(8)));
typedef short  s16x8   __attribute__((ext_vector_type(8)));
typedef float  f32x4   __attribute__((ext_vector_type(4)));

#define IN_DIM 128
#define HID    256
#define OUTD   128
#define BKT_SHIFT 7
#define BKT_NODES 128
#define MAXB 512            // max buckets (N <= 65536)
#define CAP  8192           // per-bucket capacity (mean 2046, 40+ sigma margin)
#define EBLK 512            // edge-bucketing blocks in k_pe

__device__ __forceinline__ float2 bf2f(__hip_bfloat162 v) {
    return make_float2(__bfloat162float(v.x), __bfloat162float(v.y));
}
__device__ __forceinline__ __hip_bfloat162 f2bf(float a, float b) {
    __hip_bfloat162 r; r.x = __float2bfloat16(a); r.y = __float2bfloat16(b); return r;
}
__device__ __forceinline__ void acc_row(float* acc, s16x8 r) {
    __hip_bfloat162* p = (__hip_bfloat162*)&r;
#pragma unroll
    for (int j = 0; j < 4; ++j) {
        float2 f = bf2f(p[j]);
        acc[2 * j]     += f.x;
        acc[2 * j + 1] += f.y;
    }
}

// dtype self-detection (W2 uniform +-1/16: any bf16-exp >= 0x7F => fp32)
__device__ __forceinline__ int detect_f32(const void* W2raw) {
    const unsigned short* u = (const unsigned short*)W2raw;
    int f32 = 0;
#pragma unroll
    for (int i = 0; i < 64; ++i) {
        unsigned e = (u[i] >> 7) & 0xFF;
        if (e >= 0x7F) f32 = 1;
    }
    return f32;
}
__device__ __forceinline__ int detect_i64(const void* eiraw) {
    const unsigned* ip = (const unsigned*)eiraw;
    unsigned orodd = 0;
#pragma unroll
    for (int i = 0; i < 64; ++i) orodd |= ip[2 * i + 1];
    return (orodd == 0) ? 1 : 0;
}

__device__ __forceinline__ short ldw(const void* raw, int idx, int f32) {
    if (f32) {
        __hip_bfloat16 h = __float2bfloat16(((const float*)raw)[idx]);
        return *(short*)&h;
    }
    return ((const short*)raw)[idx];
}

template <int K, int NN>
__device__ __forceinline__ void swz_one(const void* Wraw, int f32,
                                        short* __restrict__ Bsw, int tid) {
    constexpr int KC = K / 32;
    constexpr int NT = NN / 16;
    if (tid >= NT * KC * 64) return;
    int lane = tid & 63;
    int kc   = (tid >> 6) % KC;
    int nt   = tid / (64 * KC);
    int n  = nt * 16 + (lane & 15);
    int kb = kc * 32 + (lane >> 4) * 8;
    s16x8 v;
#pragma unroll
    for (int j = 0; j < 8; ++j) v[j] = ldw(Wraw, (kb + j) * NN + n, f32);
    ((s16x8*)Bsw)[tid] = v;
}

// ---------------- fused: edge bucketing + weight prep + flags ----------------

__global__ __launch_bounds__(256) void k_pe(
        const void* __restrict__ ei_, int E, int N, int NB,
        int* __restrict__ bcnt, unsigned* __restrict__ ppack,
        const void* W1raw, const void* b1raw, const void* W2raw, const void* b2raw,
        short* __restrict__ Bsw1, short* __restrict__ Bsw2,
        __hip_bfloat16* __restrict__ b1c, __hip_bfloat16* __restrict__ b2c,
        int* __restrict__ flags) {
    int blk = blockIdx.x, t = threadIdx.x;
    if (blk >= EBLK) {
        int f32 = detect_f32(W2raw);
        int pb = blk - EBLK;
        if (pb < 16) {
            swz_one<IN_DIM, HID>(W1raw, f32, Bsw1, pb * 256 + t);
        } else if (pb < 32) {
            swz_one<HID, OUTD>(W2raw, f32, Bsw2, (pb - 16) * 256 + t);
        } else {
            short s1 = ldw(b1raw, t, f32);
            b1c[t] = *(__hip_bfloat16*)&s1;
            if (t < OUTD) {
                short s2 = ldw(b2raw, t, f32);
                b2c[t] = *(__hip_bfloat16*)&s2;
            }
            if (t == 0) {
                flags[0] = f32;
                flags[1] = detect_i64(ei_);
            }
        }
        return;
    }
    __shared__ int lhist[4][MAXB];
    __shared__ int lbase[4][MAXB];
    int wv = t >> 6;
    int i64 = detect_i64(ei_);
    const long long* p64 = (const long long*)ei_;
    const int*       p32 = (const int*)ei_;
    int per = (E + EBLK - 1) / EBLK;
    int e0 = blk * per, e1 = min(e0 + per, E);
    for (int i = t; i < NB; i += 256) {
        lhist[0][i] = 0; lhist[1][i] = 0; lhist[2][i] = 0; lhist[3][i] = 0;
    }
    __syncthreads();
    for (int e = e0 + t; e < e1; e += 256) {
        int d = i64 ? (int)p64[E + e] : p32[E + e];
        if ((unsigned)d >= (unsigned)N) d = 0;
        atomicAdd(&lhist[wv][((unsigned)d) >> BKT_SHIFT], 1);
    }
    __syncthreads();
    for (int i = t; i < NB; i += 256) {
        int c0 = lhist[0][i], c1 = lhist[1][i], c2 = lhist[2][i], c3 = lhist[3][i];
        int tot = c0 + c1 + c2 + c3;
        int g = tot ? atomicAdd(&bcnt[i], tot) : 0;
        lbase[0][i] = g;
        lbase[1][i] = g + c0;
        lbase[2][i] = g + c0 + c1;
        lbase[3][i] = g + c0 + c1 + c2;
        lhist[0][i] = 0; lhist[1][i] = 0; lhist[2][i] = 0; lhist[3][i] = 0;
    }
    __syncthreads();
    for (int e = e0 + t; e < e1; e += 256) {
        int d = i64 ? (int)p64[E + e] : p32[E + e];
        int s = i64 ? (int)p64[e]     : p32[e];
        if ((unsigned)d >= (unsigned)N) d = 0;
        if ((unsigned)s >= (unsigned)N) s = 0;
        int b = ((unsigned)d) >> BKT_SHIFT;
        int pos = lbase[wv][b] + atomicAdd(&lhist[wv][b], 1);
        if (pos < CAP)
            ppack[(size_t)b * CAP + pos] = ((unsigned)(d & (BKT_NODES - 1)) << 25) | (unsigned)s;
    }
}

// ---------------- bucket sort (+bucket scan, +prescale xs) ----------------

__global__ __launch_bounds__(512) void k_bsort(const int* __restrict__ bcnt,
                                               const unsigned* __restrict__ ppack,
                                               int NB,
                                               int* __restrict__ csr, int* __restrict__ offsets,
                                               float* __restrict__ dinv, int N,
                                               const void* __restrict__ xraw,
                                               const int* __restrict__ flags,
                                               __hip_bfloat16* __restrict__ xs) {
    __shared__ int sb[MAXB];
    __shared__ int h[BKT_NODES], base[BKT_NODES], s[BKT_NODES];
    __shared__ float sdv[BKT_NODES];
    int b = blockIdx.x;
    int t = threadIdx.x;
    int c = (t < NB) ? min(bcnt[t], CAP) : 0;
    sb[t] = c;
    __syncthreads();
    for (int off = 1; off < MAXB; off <<= 1) {
        int u = (t >= off) ? sb[t - off] : 0;
        __syncthreads();
        sb[t] += u;
        __syncthreads();
    }
    int cnt   = min(bcnt[b], CAP);
    int ebase = sb[b] - cnt;
    if (b == NB - 1 && t == 0) offsets[N] = sb[b];
    const unsigned* pp = ppack + (size_t)b * CAP;
    if (t < BKT_NODES) h[t] = 0;
    __syncthreads();
    for (int e = t; e < cnt; e += 512) atomicAdd(&h[pp[e] >> 25], 1);
    __syncthreads();
    int v = (t < BKT_NODES) ? h[t] : 0;
    if (t < BKT_NODES) s[t] = v;
    __syncthreads();
    for (int off = 1; off < BKT_NODES; off <<= 1) {
        int u = (t < BKT_NODES && t >= off) ? s[t - off] : 0;
        __syncthreads();
        if (t < BKT_NODES) s[t] += u;
        __syncthreads();
    }
    if (t < BKT_NODES) {
        int excl = s[t] - v;
        base[t] = excl;
        int node = b * BKT_NODES + t;
        float dv = 0.f;
        if (node < N) {
            dv = rsqrtf((float)(v + 1));
            offsets[node] = ebase + excl;
            dinv[node] = dv;
        } else {
            dinv[node] = 0.f;
        }
        sdv[t] = dv;
        h[t] = 0;
    }
    __syncthreads();
    for (int e = t; e < cnt; e += 512) {
        unsigned pk = pp[e];
        int ld = pk >> 25;
        int pos = ebase + base[ld] + atomicAdd(&h[ld], 1);
        csr[pos] = (int)(pk & 0x1FFFFFFu);
    }
    // fused prescale: xs rows [b*128, b*128+128) = dinv * x (row-major)
    int f32 = flags[0];
    if (!f32) {
        const s16x8* xg = (const s16x8*)xraw;
        s16x8* xo = (s16x8*)xs;
        for (int u = t; u < BKT_NODES * 16; u += 512) {
            int row = u >> 4;
            int node = b * BKT_NODES + row;
            float dv = sdv[row];
            s16x8 val = {0, 0, 0, 0, 0, 0, 0, 0};
            if (node < N) {
                s16x8 xin = xg[(size_t)node * 16 + (u & 15)];
                __hip_bfloat162* xp = (__hip_bfloat162*)&xin;
                __hip_bfloat162* vp = (__hip_bfloat162*)&val;
#pragma unroll
                for (int j = 0; j < 4; ++j) {
                    float2 f = bf2f(xp[j]);
                    vp[j] = f2bf(dv * f.x, dv * f.y);
                }
            }
            xo[(size_t)node * 16 + (u & 15)] = val;
        }
    } else {
        const float4* xg = (const float4*)xraw;
        __hip_bfloat162* xo = (__hip_bfloat162*)xs;
        for (int u = t; u < BKT_NODES * 32; u += 512) {
            int row = u >> 5;
            int node = b * BKT_NODES + row;
            float dv = sdv[row];
            __hip_bfloat162 v0 = f2bf(0.f, 0.f), v1 = v0;
            if (node < N) {
                float4 xin = xg[(size_t)node * 32 + (u & 31)];
                v0 = f2bf(dv * xin.x, dv * xin.y);
                v1 = f2bf(dv * xin.z, dv * xin.w);
            }
            xo[(size_t)node * 64 + (u & 31) * 2]     = v0;
            xo[(size_t)node * 64 + (u & 31) * 2 + 1] = v1;
        }
    }
}

// ---------------- aggregation 1 (per-group-node gather) ----------------
// 16-lane group owns one node: all its edges (contiguous csr), lane = 16B
// granule. No butterfly, no idle lanes; 256B coalesced output per group.

__global__ __launch_bounds__(256) void k_agg1(
        const s16x8* __restrict__ xs8, const int* __restrict__ offsets,
        const int* __restrict__ csr, const float* __restrict__ dinv,
        s16x8* __restrict__ a8, int N, int Npad) {
    int gw   = blockIdx.x * 4 + (threadIdx.x >> 6);
    int lane = threadIdx.x & 63;
    int quad = lane >> 4, l16 = lane & 15;
    int v = gw * 4 + quad;                 // group's node (single pass)
    if (v >= Npad) return;
    const char* xb = (const char*)xs8;
    unsigned go = ((unsigned)v << 8) | ((unsigned)l16 << 4);
    if (v >= N) {
        s16x8 z = {0, 0, 0, 0, 0, 0, 0, 0};
        *(s16x8*)((char*)a8 + go) = z;
        return;
    }
    float acc[8];
#pragma unroll
    for (int j = 0; j < 8; ++j) acc[j] = 0.f;
    int o0 = offsets[v], o1 = offsets[v + 1];
    acc_row(acc, *(const s16x8*)(xb + go));     // self (pre-scaled)
    int e = o0;
    for (; e + 3 < o1; e += 4) {
        int s0 = __builtin_nontemporal_load(&csr[e]);
        int s1 = __builtin_nontemporal_load(&csr[e + 1]);
        int s2 = __builtin_nontemporal_load(&csr[e + 2]);
        int s3 = __builtin_nontemporal_load(&csr[e + 3]);
        s16x8 r0 = *(const s16x8*)(xb + (((unsigned)s0 << 8) | ((unsigned)l16 << 4)));
        s16x8 r1 = *(const s16x8*)(xb + (((unsigned)s1 << 8) | ((unsigned)l16 << 4)));
        s16x8 r2 = *(const s16x8*)(xb + (((unsigned)s2 << 8) | ((unsigned)l16 << 4)));
        s16x8 r3 = *(const s16x8*)(xb + (((unsigned)s3 << 8) | ((unsigned)l16 << 4)));
        acc_row(acc, r0); acc_row(acc, r1); acc_row(acc, r2); acc_row(acc, r3);
    }
    for (; e < o1; ++e) {
        int s0 = __builtin_nontemporal_load(&csr[e]);
        acc_row(acc, *(const s16x8*)(xb + (((unsigned)s0 << 8) | ((unsigned)l16 << 4))));
    }
    float dv = dinv[v];
    s16x8 outv;
    __hip_bfloat162* op = (__hip_bfloat162*)&outv;
#pragma unroll
    for (int j = 0; j < 4; ++j) op[j] = f2bf(dv * acc[2 * j], dv * acc[2 * j + 1]);
    *(s16x8*)((char*)a8 + go) = outv;
}

// ---------------- fused MFMA GEMM1+GEMM2 (64-row tiles) ----------------
// Block = 4 waves, 64 rows/tile, wave owns 16 rows. Phase 1: h1 = relu(A@W1+b1)
// into XOR-swizzled LDS (per-wave-private rows, no barrier). Phase 2:
// h2s = (h1@W2)*dinv. LDS granule swizzle: g = gcol ^ (row&31), 16B granules.

__global__ __launch_bounds__(256) void k_gemm12(
        const __hip_bfloat16* __restrict__ A, const __hip_bfloat16* __restrict__ Bsw1,
        const __hip_bfloat16* __restrict__ b1c, const __hip_bfloat16* __restrict__ Bsw2,
        const float* __restrict__ dinv, __hip_bfloat16* __restrict__ h2s) {
    __shared__ __align__(16) __hip_bfloat16 hl[64 * HID];   // 32 KB
    int wave = threadIdx.x >> 6, lane = threadIdx.x & 63;
    int quad = lane >> 4, l16 = lane & 15;
    int mw = wave * 16;                    // wave row base in tile
    int gm = blockIdx.x * 64 + mw;         // global row base

    // phase 1
    bf16x8v a1f[4];
#pragma unroll
    for (int kc = 0; kc < 4; ++kc)
        a1f[kc] = *reinterpret_cast<const bf16x8v*>(
            A + (size_t)(gm + l16) * IN_DIM + kc * 32 + quad * 8);

    const bf16x8v* B1 = reinterpret_cast<const bf16x8v*>(Bsw1);
    for (int nt = 0; nt < HID / 16; ++nt) {
        f32x4 acc = {0.f, 0.f, 0.f, 0.f};
#pragma unroll
        for (int kc = 0; kc < 4; ++kc)
            acc = __builtin_amdgcn_mfma_f32_16x16x32_bf16(a1f[kc], B1[(nt * 4 + kc) * 64 + lane], acc, 0, 0, 0);
        int col = nt * 16 + l16;
        int gcol = col >> 3, csub = col & 7;
        float bv = __bfloat162float(b1c[col]);
#pragma unroll
        for (int r = 0; r < 4; ++r) {
            float v0 = acc[r] + bv; v0 = v0 > 0.f ? v0 : 0.f;
            int r0 = mw + quad * 4 + r;
            ((__hip_bfloat16*)((char*)hl + (size_t)r0 * (HID * 2) + ((gcol ^ (r0 & 31)) << 4)))[csub] = __float2bfloat16(v0);
        }
    }
    // per-wave-private rows: no __syncthreads needed

    // phase 2
    bf16x8v a2f[8];
#pragma unroll
    for (int kc = 0; kc < 8; ++kc) {
        int row = mw + l16;
        int g = (kc * 4 + quad) ^ (row & 31);
        a2f[kc] = *reinterpret_cast<const bf16x8v*>(
            (char*)hl + (size_t)row * (HID * 2) + ((size_t)g << 4));
    }
    const bf16x8v* B2 = reinterpret_cast<const bf16x8v*>(Bsw2);
    int rb0 = gm + quad * 4;
    float sc0[4];
#pragma unroll
    for (int r = 0; r < 4; ++r) sc0[r] = dinv[rb0 + r];
    for (int nt = 0; nt < OUTD / 16; ++nt) {
        f32x4 acc = {0.f, 0.f, 0.f, 0.f};
#pragma unroll
        for (int kc = 0; kc < 8; ++kc)
            acc = __builtin_amdgcn_mfma_f32_16x16x32_bf16(a2f[kc], B2[(nt * 8 + kc) * 64 + lane], acc, 0, 0, 0);
        int col = nt * 16 + l16;
#pragma unroll
        for (int r = 0; r < 4; ++r)
            h2s[(size_t)(rb0 + r) * OUTD + col] = __float2bfloat16(acc[r] * sc0[r]);
    }
}

// ---------------- aggregation 2 (per-group-node gather) ----------------

__global__ __launch_bounds__(256) void k_agg2(
        const s16x8* __restrict__ h8, const int* __restrict__ offsets,
        const int* __restrict__ csr, const float* __restrict__ dinv,
        const __hip_bfloat16* __restrict__ b2c, const int* __restrict__ flags,
        void* __restrict__ outraw, int N) {
    int gw   = blockIdx.x * 4 + (threadIdx.x >> 6);
    int lane = threadIdx.x & 63;
    int quad = lane >> 4, l16 = lane & 15;
    int f32 = flags[0];
    const char* hb = (const char*)h8;
    float bb[8];
    {
        s16x8 bv = ((const s16x8*)b2c)[l16];
        __hip_bfloat162* bp = (__hip_bfloat162*)&bv;
#pragma unroll
        for (int j = 0; j < 4; ++j) {
            float2 f = bf2f(bp[j]);
            bb[2 * j] = f.x; bb[2 * j + 1] = f.y;
        }
    }
    int v = gw * 4 + quad;                 // group's node (single pass)
    if (v >= N) return;
    float acc[8];
#pragma unroll
    for (int j = 0; j < 8; ++j) acc[j] = 0.f;
    int o0 = offsets[v], o1 = offsets[v + 1];
    acc_row(acc, *(const s16x8*)(hb + (((unsigned)v << 8) | ((unsigned)l16 << 4))));  // self
    int e = o0;
    for (; e + 3 < o1; e += 4) {
        int s0 = __builtin_nontemporal_load(&csr[e]);
        int s1 = __builtin_nontemporal_load(&csr[e + 1]);
        int s2 = __builtin_nontemporal_load(&csr[e + 2]);
        int s3 = __builtin_nontemporal_load(&csr[e + 3]);
        s16x8 r0 = *(const s16x8*)(hb + (((unsigned)s0 << 8) | ((unsigned)l16 << 4)));
        s16x8 r1 = *(const s16x8*)(hb + (((unsigned)s1 << 8) | ((unsigned)l16 << 4)));
        s16x8 r2 = *(const s16x8*)(hb + (((unsigned)s2 << 8) | ((unsigned)l16 << 4)));
        s16x8 r3 = *(const s16x8*)(hb + (((unsigned)s3 << 8) | ((unsigned)l16 << 4)));
        acc_row(acc, r0); acc_row(acc, r1); acc_row(acc, r2); acc_row(acc, r3);
    }
    for (; e < o1; ++e) {
        int s0 = __builtin_nontemporal_load(&csr[e]);
        acc_row(acc, *(const s16x8*)(hb + (((unsigned)s0 << 8) | ((unsigned)l16 << 4))));
    }
    float dv = dinv[v];
    if (f32) {
        f32x4* of = (f32x4*)outraw;
        f32x4 o0v = {dv * acc[0] + bb[0], dv * acc[1] + bb[1],
                     dv * acc[2] + bb[2], dv * acc[3] + bb[3]};
        f32x4 o1v = {dv * acc[4] + bb[4], dv * acc[5] + bb[5],
                     dv * acc[6] + bb[6], dv * acc[7] + bb[7]};
        __builtin_nontemporal_store(o0v, &of[(size_t)v * 32 + l16 * 2]);
        __builtin_nontemporal_store(o1v, &of[(size_t)v * 32 + l16 * 2 + 1]);
    } else {
        s16x8 outv;
        __hip_bfloat162* op = (__hip_bfloat162*)&outv;
#pragma unroll
        for (int j = 0; j < 4; ++j)
            op[j] = f2bf(dv * acc[2 * j] + bb[2 * j], dv * acc[2 * j + 1] + bb[2 * j + 1]);
        __builtin_nontemporal_store(outv, &((s16x8*)outraw)[(size_t)v * 16 + l16]);
    }
}

// ---------------- host launch ----------------

extern "C" void kernel_launch(void* const* d_in, const int* in_sizes, int n_in,
                              void* d_out, int out_size, void* d_ws, size_t ws_size,
                              hipStream_t stream) {
    const void* x  = d_in[0];
    const void* ei = d_in[1];
    const void* W1 = d_in[2];
    const void* b1 = d_in[3];
    const void* W2 = d_in[4];
    const void* b2 = d_in[5];

    const int N = in_sizes[0] / IN_DIM;       // 50000
    const int E = in_sizes[1] / 2;            // 800000
    const int Npad = ((N + 127) / 128) * 128; // 50048 (multiple of 128)
    const int NB = Npad / BKT_NODES;          // 391

    char* w = (char*)d_ws;
    auto alloc = [&](size_t bytes) -> void* {
        void* p = (void*)w;
        w += (bytes + 255) / 256 * 256;
        return p;
    };
    int*   flags   = (int*)alloc(256);
    int*   bcnt    = (int*)alloc((size_t)MAXB * 4);
    int*   offsets = (int*)alloc((size_t)(N + 1) * 4);
    float* dinv    = (float*)alloc((size_t)Npad * 4);
    unsigned* ppack = (unsigned*)alloc((size_t)NB * CAP * 4);
    int*   csr     = (int*)alloc((size_t)E * 4);
    short* Bsw1 = (short*)alloc((size_t)IN_DIM * HID * 2);
    short* Bsw2 = (short*)alloc((size_t)HID * OUTD * 2);
    __hip_bfloat16* b1c = (__hip_bfloat16*)alloc((size_t)HID * 2);
    __hip_bfloat16* b2c = (__hip_bfloat16*)alloc((size_t)OUTD * 2);
    __hip_bfloat16* xs  = (__hip_bfloat16*)alloc((size_t)Npad * IN_DIM * 2);
    __hip_bfloat16* a1  = (__hip_bfloat16*)alloc((size_t)Npad * IN_DIM * 2);
    __hip_bfloat16* h2s = xs;   // xs dead after agg1; reuse for gemm12 output

    hipMemsetAsync(bcnt, 0, (size_t)MAXB * 4, stream);

    k_pe<<<EBLK + 33, 256, 0, stream>>>(ei, E, N, NB, bcnt, ppack,
                                        W1, b1, W2, b2, Bsw1, Bsw2, b1c, b2c, flags);

    k_bsort<<<NB, 512, 0, stream>>>(bcnt, ppack, NB, csr, offsets, dinv, N,
                                    x, flags, xs);

    k_agg1<<<Npad / 16, 256, 0, stream>>>((const s16x8*)xs, offsets, csr, dinv,
                                          (s16x8*)a1, N, Npad);

    k_gemm12<<<Npad / 64, 256, 0, stream>>>(a1, (const __hip_bfloat16*)Bsw1, b1c,
                                            (const __hip_bfloat16*)Bsw2, dinv, h2s);

    const int agg2Blocks = (N + 15) / 16;   // one node per 16-lane group
    k_agg2<<<agg2Blocks, 256, 0, stream>>>((const s16x8*)h2s, offsets, csr, dinv,
                                           b2c, flags, d_out, N);
}